// Round 9
// baseline (98.078 us; speedup 1.0000x reference)
//
#include <hip/hip_runtime.h>

// Vanilla RNN B=4096 S=512 I=1 H=16 O=1 — serial-chain latency optimization.
// Lane = (batch, h-row); 16 lanes/batch; 1024 waves = 1 wave/SIMD (hard cap).
// Wall time = 512 * per-step critical-path latency.
//
// R8: single-trans short-hop tail. R7 decomposition: front ~54 cyc, tail
// (exp->add->rcp) ~100 cyc => v_exp/v_rcp solo-wave dep latency ~40 each.
// Replace tail with:
//   u = exp2(-|s|)            (one v_exp_f32; -|x| via free src modifiers)
//   P(u) ~= 1/(1+u), deg-4 Chebyshev on [0,1], max err ~1.8e-4
//   g = P * (s>=0 ? u : 1)    (exact: 1/(1+2^s) = u*P(u) if s>=0 else P(u))
// cmp/cndmask run parallel to the poly; serial tail = exp + 3 fma + mul.
// Also: s_nop dropped — asm head = 2 non-DPP fmacs (bias+g*w0, +x*wih),
// satisfying the 2-wait-state VALU-write->DPP-read hazard naturally.
//
// Front kept from R7: 16 v_fmac_f32_dpp/v_mul_f32_dpp row_ror:N, weights
// self-calibrated against the HW's actual rotation (R1-validated).
// Load pipeline kept from R6 (staged 16-step blocks, no per-iter drain).
// g-trick: h = 1-2g; rowsum(W_hh) in bias, -2*S2LE in weights.

#define S2LE 2.8853900817779268f  // 2*log2(e)

// deg-4 monomial coefficients of ~1/(1+u) on [0,1] (Chebyshev-truncated)
#define PB0  0.9997464f
#define PB1 -0.9861170f
#define PB2  0.8720012f
#define PB3 -0.5423312f
#define PB4  0.1568800f

typedef float float4_ __attribute__((ext_vector_type(4)));

#define ROTI(v, N) __builtin_amdgcn_mov_dpp((v), 0x120 + (N), 0xF, 0xF, 0)
#define ROTF(v, N) __int_as_float(__builtin_amdgcn_mov_dpp(__float_as_int(v), 0x120 + (N), 0xF, 0xF, 0))

__global__ __launch_bounds__(64) void rnn_kernel(
    const float* __restrict__ x,
    const float* __restrict__ W_ih,
    const float* __restrict__ W_hh,
    const float* __restrict__ b_ih,
    const float* __restrict__ b_hh,
    const float* __restrict__ W_fc,
    const float* __restrict__ b_fc,
    float* __restrict__ out)
{
    const int li = (int)(threadIdx.x & 15u);
    const int b  = (int)((blockIdx.x * 64u + threadIdx.x) >> 4);

    const float* __restrict__ row = W_hh + li * 16;

    float sw = 0.0f;
#pragma unroll
    for (int j = 0; j < 16; ++j) sw += row[j];

    const float wsc = -2.0f * S2LE;

    // Self-calibrated weights: w[N] = wsc * W[li][sigma_N(li)], sigma_N =
    // the HW's row_ror:N permutation (validated end-to-end in R1/R7).
    float w0  = wsc * row[li];
    float w1  = wsc * row[ROTI(li, 1)];
    float w2  = wsc * row[ROTI(li, 2)];
    float w3  = wsc * row[ROTI(li, 3)];
    float w4  = wsc * row[ROTI(li, 4)];
    float w5  = wsc * row[ROTI(li, 5)];
    float w6  = wsc * row[ROTI(li, 6)];
    float w7  = wsc * row[ROTI(li, 7)];
    float w8  = wsc * row[ROTI(li, 8)];
    float w9  = wsc * row[ROTI(li, 9)];
    float w10 = wsc * row[ROTI(li, 10)];
    float w11 = wsc * row[ROTI(li, 11)];
    float w12 = wsc * row[ROTI(li, 12)];
    float w13 = wsc * row[ROTI(li, 13)];
    float w14 = wsc * row[ROTI(li, 14)];
    float w15 = wsc * row[ROTI(li, 15)];

    const float wih  = W_ih[li] * S2LE;
    const float bias = (b_ih[li] + b_hh[li] + sw) * S2LE;
    const float wfc  = W_fc[li];
    const float bfc  = b_fc[0];

    const float4_* __restrict__ xv = (const float4_*)(x + (size_t)b * 512);

    float g = 0.5f;  // represents h = 0

    // One step. asm: head = 2 non-DPP fmacs (covers the DPP hazard), then
    // 3 DPP seeds + 12 DPP fmacs in 4 round-robin chains. Tail: tree add,
    // u=exp2(-|s|), deg-4 poly (Estrin), side cndmask, final mul.
#define STEP(XT) do { \
    float a0 = bias, a1, a2, a3; \
    asm volatile( \
        "v_fmac_f32 %0, %4, %6\n\t"  /* a0 += g*w0   (non-DPP, hazard slot 1) */ \
        "v_fmac_f32 %0, %5, %21\n\t" /* a0 += xt*wih (non-DPP, hazard slot 2) */ \
        "v_mul_f32_dpp %1, %4, %10  row_ror:4  row_mask:0xf bank_mask:0xf\n\t" \
        "v_mul_f32_dpp %2, %4, %14 row_ror:8  row_mask:0xf bank_mask:0xf\n\t" \
        "v_mul_f32_dpp %3, %4, %18 row_ror:12 row_mask:0xf bank_mask:0xf\n\t" \
        "v_fmac_f32_dpp %0, %4, %7  row_ror:1  row_mask:0xf bank_mask:0xf\n\t" \
        "v_fmac_f32_dpp %1, %4, %11 row_ror:5  row_mask:0xf bank_mask:0xf\n\t" \
        "v_fmac_f32_dpp %2, %4, %15 row_ror:9  row_mask:0xf bank_mask:0xf\n\t" \
        "v_fmac_f32_dpp %3, %4, %19 row_ror:13 row_mask:0xf bank_mask:0xf\n\t" \
        "v_fmac_f32_dpp %0, %4, %8  row_ror:2  row_mask:0xf bank_mask:0xf\n\t" \
        "v_fmac_f32_dpp %1, %4, %12 row_ror:6  row_mask:0xf bank_mask:0xf\n\t" \
        "v_fmac_f32_dpp %2, %4, %16 row_ror:10 row_mask:0xf bank_mask:0xf\n\t" \
        "v_fmac_f32_dpp %3, %4, %20 row_ror:14 row_mask:0xf bank_mask:0xf\n\t" \
        "v_fmac_f32_dpp %0, %4, %9  row_ror:3  row_mask:0xf bank_mask:0xf\n\t" \
        "v_fmac_f32_dpp %1, %4, %13 row_ror:7  row_mask:0xf bank_mask:0xf\n\t" \
        "v_fmac_f32_dpp %2, %4, %17 row_ror:11 row_mask:0xf bank_mask:0xf\n\t" \
        "v_fmac_f32_dpp %3, %4, %22 row_ror:15 row_mask:0xf bank_mask:0xf\n\t" \
        : "+v"(a0), "=&v"(a1), "=&v"(a2), "=&v"(a3) \
        : "v"(g), "v"(XT), \
          "v"(w0),  "v"(w1),  "v"(w2),  "v"(w3), \
          "v"(w4),  "v"(w5),  "v"(w6),  "v"(w7), \
          "v"(w8),  "v"(w9),  "v"(w10), "v"(w11), \
          "v"(w12), "v"(w13), "v"(w14), "v"(wih), "v"(w15)); \
    float s_ = (a0 + a1) + (a2 + a3); \
    float u_ = __builtin_amdgcn_exp2f(-fabsf(s_));  /* -|s| via src mods */ \
    float u2_ = u_ * u_; \
    float e0_ = fmaf(u_, PB1, PB0); \
    float e1_ = fmaf(u_, PB3, PB2); \
    float u4_ = u2_ * u2_; \
    float f0_ = fmaf(u2_, e1_, e0_); \
    float P_  = fmaf(u4_, PB4, f0_); \
    float sel_ = (s_ >= 0.0f) ? u_ : 1.0f;  /* cmp/cndmask, off-path */ \
    g = P_ * sel_; \
} while (0)

// 16 recurrent steps from a 4-x-float4 staged block.
#define BLOCK(BUF) do { \
    _Pragma("unroll") \
    for (int j = 0; j < 4; ++j) { \
        STEP((BUF)[j][0]); \
        STEP((BUF)[j][1]); \
        STEP((BUF)[j][2]); \
        STEP((BUF)[j][3]); \
    } \
} while (0)

    float4_ bufA[4], bufB[4];
#pragma unroll
    for (int j = 0; j < 4; ++j) bufA[j] = xv[j];  // block 0

    // Unroll-2 modulo pipeline over 32 blocks of 16 timesteps (R6): loads
    // issue one full block ahead; no register rotation, no per-iter drain.
#pragma unroll 1
    for (int i = 0; i < 32; i += 2) {
#pragma unroll
        for (int j = 0; j < 4; ++j) bufB[j] = xv[(4 * (i + 1) + j) & 127];
        BLOCK(bufA);
#pragma unroll
        for (int j = 0; j < 4; ++j) bufA[j] = xv[(4 * (i + 2) + j) & 127];
        BLOCK(bufB);
    }
#undef BLOCK
#undef STEP

    // out[b] = sum_i wfc_i * h_i + bfc,  h = 1 - 2g (f32 g).
    float p = fmaf(-2.0f * wfc, g, wfc);
    p += ROTF(p, 8);
    p += ROTF(p, 4);
    p += ROTF(p, 2);
    p += ROTF(p, 1);
    if (li == 0) out[b] = p + bfc;
}

extern "C" void kernel_launch(void* const* d_in, const int* in_sizes, int n_in,
                              void* d_out, int out_size, void* d_ws, size_t ws_size,
                              hipStream_t stream) {
    const float* x    = (const float*)d_in[0];
    const float* W_ih = (const float*)d_in[1];
    const float* W_hh = (const float*)d_in[2];
    const float* b_ih = (const float*)d_in[3];
    const float* b_hh = (const float*)d_in[4];
    const float* W_fc = (const float*)d_in[5];
    const float* b_fc = (const float*)d_in[6];
    float* out = (float*)d_out;

    rnn_kernel<<<1024, 64, 0, stream>>>(x, W_ih, W_hh, b_ih, b_hh, W_fc, b_fc, out);
}